// Round 1
// baseline (2239.850 us; speedup 1.0000x reference)
//
#include <hip/hip_runtime.h>
#include <hip/hip_bf16.h>

#define N_NODES 50000
#define M_EDGES 800000
#define LEAKY_F 0.2f
#define BN_EPS 1e-5f

__device__ __forceinline__ float leaky(float x) { return x >= 0.f ? x : LEAKY_F * x; }

// ---- scatter add: out[dst[e]] += in[src[e]] (rows of 64 floats), float4 per thread ----
__global__ __launch_bounds__(256) void scatter_add_k(
    float* __restrict__ out, const float* __restrict__ in,
    const int* __restrict__ src, const int* __restrict__ dst) {
  int t = blockIdx.x * blockDim.x + threadIdx.x;
  if (t >= M_EDGES * 16) return;
  int e = t >> 4, q = t & 15;
  int s = src[e], d = dst[e];
  float4 v = reinterpret_cast<const float4*>(in)[(size_t)s * 16 + q];
  float* o = out + (size_t)d * 64 + q * 4;
  atomicAdd(o + 0, v.x);
  atomicAdd(o + 1, v.y);
  atomicAdd(o + 2, v.z);
  atomicAdd(o + 3, v.w);
}

// ---- node1: s1 = A@W0+b0 ; s2 = A@W1 + s1@W2 + b1+b2   (row-local, 4 rows/block) ----
__global__ __launch_bounds__(256) void node1_k(
    const float* __restrict__ A, const float* __restrict__ W_ops,
    const float* __restrict__ b_ops, float* __restrict__ s1g, float* __restrict__ s2g) {
  __shared__ float W0[4096], W1[4096], W2[4096];
  __shared__ float rA[4][64], r1[4][64];
  int tid = threadIdx.x;
  for (int i = tid; i < 4096; i += 256) {
    W0[i] = W_ops[i];
    W1[i] = W_ops[4096 + i];
    W2[i] = W_ops[8192 + i];
  }
  int g = tid >> 6, j = tid & 63;
  size_t r = (size_t)blockIdx.x * 4 + g;   // N divisible by 4 -> always valid
  rA[g][j] = A[r * 64 + j];
  __syncthreads();
  float acc = b_ops[j];
#pragma unroll
  for (int k = 0; k < 64; ++k) acc = fmaf(rA[g][k], W0[k * 64 + j], acc);
  r1[g][j] = acc;
  s1g[r * 64 + j] = acc;
  __syncthreads();
  float acc2 = b_ops[64 + j] + b_ops[128 + j];
#pragma unroll
  for (int k = 0; k < 64; ++k) {
    acc2 = fmaf(rA[g][k], W1[k * 64 + j], acc2);
    acc2 = fmaf(r1[g][k], W2[k * 64 + j], acc2);
  }
  s2g[r * 64 + j] = acc2;
}

// ---- node2: s3 = B@W3 + s2@W4 + b3+b4 ; Vnew = s1@Wc0+s2@Wc1+s3@Wc2+bcat ;
//             Ps = Vnew@Ws[0:64]+bS ; Pd = Vnew@Ws[128:192] ----
__global__ __launch_bounds__(256) void node2_k(
    const float* __restrict__ Bg, const float* __restrict__ s1g, const float* __restrict__ s2g,
    const float* __restrict__ W_ops, const float* __restrict__ b_ops,
    const float* __restrict__ W_cat, const float* __restrict__ b_cat,
    const float* __restrict__ W_S, const float* __restrict__ b_S,
    float* __restrict__ Vnew, float* __restrict__ Ps, float* __restrict__ Pd) {
  __shared__ float W3[4096], W4[4096], Wc0[4096], Wc1[4096], Wc2[4096], Ws0[4096], Ws2[4096];
  __shared__ float rB[4][64], r1[4][64], r2[4][64], r3[4][64], rV[4][64];
  int tid = threadIdx.x;
  for (int i = tid; i < 4096; i += 256) {
    W3[i] = W_ops[3 * 4096 + i];
    W4[i] = W_ops[4 * 4096 + i];
    Wc0[i] = W_cat[i];
    Wc1[i] = W_cat[4096 + i];
    Wc2[i] = W_cat[8192 + i];
    Ws0[i] = W_S[i];
    Ws2[i] = W_S[8192 + i];
  }
  int g = tid >> 6, j = tid & 63;
  size_t r = (size_t)blockIdx.x * 4 + g;
  rB[g][j] = Bg[r * 64 + j];
  r1[g][j] = s1g[r * 64 + j];
  r2[g][j] = s2g[r * 64 + j];
  __syncthreads();
  float a3 = b_ops[192 + j] + b_ops[256 + j];
#pragma unroll
  for (int k = 0; k < 64; ++k) {
    a3 = fmaf(rB[g][k], W3[k * 64 + j], a3);
    a3 = fmaf(r2[g][k], W4[k * 64 + j], a3);
  }
  r3[g][j] = a3;
  __syncthreads();
  float v = b_cat[j];
#pragma unroll
  for (int k = 0; k < 64; ++k) {
    v = fmaf(r1[g][k], Wc0[k * 64 + j], v);
    v = fmaf(r2[g][k], Wc1[k * 64 + j], v);
    v = fmaf(r3[g][k], Wc2[k * 64 + j], v);
  }
  rV[g][j] = v;
  Vnew[r * 64 + j] = v;
  __syncthreads();
  float ps = b_S[j], pd = 0.f;
#pragma unroll
  for (int k = 0; k < 64; ++k) {
    ps = fmaf(rV[g][k], Ws0[k * 64 + j], ps);
    pd = fmaf(rV[g][k], Ws2[k * 64 + j], pd);
  }
  Ps[r * 64 + j] = ps;
  Pd[r * 64 + j] = pd;
}

// ---- edge: Eout[e] = Ps[src[e]] + Pd[dst[e]] + leaky(E[e]) @ Wmid  (64 edges/block) ----
__global__ __launch_bounds__(256) void edge_k(
    const float* __restrict__ Eg, const int* __restrict__ src, const int* __restrict__ dst,
    const float* __restrict__ Ps, const float* __restrict__ Pd,
    const float* __restrict__ W_S, float* __restrict__ Eout) {
  __shared__ float Wm[4096];
  __shared__ float Ea[64][65];   // +1 pad: conflict-free b32 reads
  int tid = threadIdx.x;
  for (int i = tid; i < 4096; i += 256) Wm[i] = W_S[4096 + i];
  int e0 = blockIdx.x * 64;
  for (int q = tid; q < 1024; q += 256) {
    int e = q >> 4, kq = q & 15;
    float4 vv = reinterpret_cast<const float4*>(Eg)[(size_t)(e0 + e) * 16 + kq];
    Ea[e][kq * 4 + 0] = leaky(vv.x);
    Ea[e][kq * 4 + 1] = leaky(vv.y);
    Ea[e][kq * 4 + 2] = leaky(vv.z);
    Ea[e][kq * 4 + 3] = leaky(vv.w);
  }
  __syncthreads();
  int eq = tid & 15, cq = tid >> 4;   // 4 edges x 4 cols per thread
  int eb = eq * 4;
  float acc[4][4];
#pragma unroll
  for (int i = 0; i < 4; ++i) {
    int e = e0 + eb + i;
    int s = src[e], d = dst[e];
    float4 ps = reinterpret_cast<const float4*>(Ps)[(size_t)s * 16 + cq];
    float4 pd = reinterpret_cast<const float4*>(Pd)[(size_t)d * 16 + cq];
    acc[i][0] = ps.x + pd.x;
    acc[i][1] = ps.y + pd.y;
    acc[i][2] = ps.z + pd.z;
    acc[i][3] = ps.w + pd.w;
  }
#pragma unroll 8
  for (int k = 0; k < 64; ++k) {
    float4 w = *reinterpret_cast<const float4*>(&Wm[k * 64 + cq * 4]);
#pragma unroll
    for (int i = 0; i < 4; ++i) {
      float ea = Ea[eb + i][k];
      acc[i][0] = fmaf(ea, w.x, acc[i][0]);
      acc[i][1] = fmaf(ea, w.y, acc[i][1]);
      acc[i][2] = fmaf(ea, w.z, acc[i][2]);
      acc[i][3] = fmaf(ea, w.w, acc[i][3]);
    }
  }
#pragma unroll
  for (int i = 0; i < 4; ++i) {
    float4 st = make_float4(acc[i][0], acc[i][1], acc[i][2], acc[i][3]);
    reinterpret_cast<float4*>(Eout)[(size_t)(e0 + eb + i) * 16 + cq] = st;
  }
}

// ---- per-column sum / sumsq over rows (col = index % 64) ----
__global__ __launch_bounds__(256) void col_stats_k(
    const float* __restrict__ X, size_t nelem, float* __restrict__ sums) {
  __shared__ float ls[128];
  int tid = threadIdx.x;
  if (tid < 128) ls[tid] = 0.f;
  __syncthreads();
  int j = tid & 63;
  float s = 0.f, ss = 0.f;
  size_t stride = (size_t)gridDim.x * blockDim.x;   // multiple of 64
  for (size_t i = (size_t)blockIdx.x * blockDim.x + tid; i < nelem; i += stride) {
    float x = X[i];
    s += x;
    ss = fmaf(x, x, ss);
  }
  atomicAdd(&ls[j], s);
  atomicAdd(&ls[64 + j], ss);
  __syncthreads();
  if (tid < 128) atomicAdd(&sums[tid], ls[tid]);
}

__global__ void finalize_k(const float* __restrict__ sums, float inv_n,
                           const float* __restrict__ gamma, const float* __restrict__ beta,
                           float* __restrict__ sc_shift) {
  int j = threadIdx.x;   // 64 threads
  float mu = sums[j] * inv_n;
  float var = sums[64 + j] * inv_n - mu * mu;
  float sc = gamma[j] * rsqrtf(var + BN_EPS);
  sc_shift[j] = sc;
  sc_shift[64 + j] = beta[j] - mu * sc;
}

// ---- in-place: X = leaky(X*sc + shift) + resid ----
__global__ __launch_bounds__(256) void bn_apply_k(
    float* __restrict__ X, const float* __restrict__ resid,
    const float* __restrict__ sc_shift, int n4) {
  int i = blockIdx.x * blockDim.x + threadIdx.x;
  if (i >= n4) return;
  int jq = i & 15;
  float4 x = reinterpret_cast<float4*>(X)[i];
  float4 r = reinterpret_cast<const float4*>(resid)[i];
  float4 sc = reinterpret_cast<const float4*>(sc_shift)[jq];
  float4 sh = reinterpret_cast<const float4*>(sc_shift + 64)[jq];
  float4 y;
  y.x = leaky(fmaf(x.x, sc.x, sh.x)) + r.x;
  y.y = leaky(fmaf(x.y, sc.y, sh.y)) + r.y;
  y.z = leaky(fmaf(x.z, sc.z, sh.z)) + r.z;
  y.w = leaky(fmaf(x.w, sc.w, sh.w)) + r.w;
  reinterpret_cast<float4*>(X)[i] = y;
}

extern "C" void kernel_launch(void* const* d_in, const int* in_sizes, int n_in,
                              void* d_out, int out_size, void* d_ws, size_t ws_size,
                              hipStream_t stream) {
  const float* V      = (const float*)d_in[0];
  const float* Eg     = (const float*)d_in[1];
  const int*   src    = (const int*)d_in[2];
  const int*   dst    = (const int*)d_in[3];
  const float* W_ops  = (const float*)d_in[4];
  const float* b_ops  = (const float*)d_in[5];
  const float* W_cat  = (const float*)d_in[6];
  const float* b_cat  = (const float*)d_in[7];
  const float* W_S    = (const float*)d_in[8];
  const float* b_S    = (const float*)d_in[9];
  const float* gammaV = (const float*)d_in[10];
  const float* betaV  = (const float*)d_in[11];
  const float* gammaE = (const float*)d_in[12];
  const float* betaE  = (const float*)d_in[13];

  float* ws = (float*)d_ws;
  const size_t ND = (size_t)N_NODES * 64;
  float* A      = ws;             // segsum(V)
  float* s1     = ws + ND;
  float* s2     = ws + 2 * ND;
  float* Bg     = ws + 3 * ND;    // segsum(s1)
  float* Ps     = ws + 4 * ND;
  float* Pd     = ws + 5 * ND;
  float* statsV = ws + 6 * ND;    // 128 sums | 128 sums | 128 scsh | 128 scsh
  float* statsE = statsV + 128;
  float* scshV  = statsV + 256;
  float* scshE  = statsV + 384;

  float* Vout = (float*)d_out;
  float* EoutP = Vout + ND;       // E region of d_out (holds E_new pre-BN, then E_out)

  hipMemsetAsync(A, 0, ND * sizeof(float), stream);
  hipMemsetAsync(Bg, 0, ND * sizeof(float), stream);
  hipMemsetAsync(statsV, 0, 256 * sizeof(float), stream);

  const int sc_blocks = (M_EDGES * 16 + 255) / 256;
  scatter_add_k<<<sc_blocks, 256, 0, stream>>>(A, V, src, dst);
  node1_k<<<N_NODES / 4, 256, 0, stream>>>(A, W_ops, b_ops, s1, s2);
  scatter_add_k<<<sc_blocks, 256, 0, stream>>>(Bg, s1, src, dst);
  node2_k<<<N_NODES / 4, 256, 0, stream>>>(Bg, s1, s2, W_ops, b_ops, W_cat, b_cat,
                                           W_S, b_S, Vout, Ps, Pd);
  edge_k<<<M_EDGES / 64, 256, 0, stream>>>(Eg, src, dst, Ps, Pd, W_S, EoutP);
  col_stats_k<<<1024, 256, 0, stream>>>(Vout, ND, statsV);
  col_stats_k<<<2048, 256, 0, stream>>>(EoutP, (size_t)M_EDGES * 64, statsE);
  finalize_k<<<1, 64, 0, stream>>>(statsV, 1.f / N_NODES, gammaV, betaV, scshV);
  finalize_k<<<1, 64, 0, stream>>>(statsE, 1.f / M_EDGES, gammaE, betaE, scshE);
  bn_apply_k<<<(int)((ND / 4 + 255) / 256), 256, 0, stream>>>(Vout, V, scshV, (int)(ND / 4));
  bn_apply_k<<<(M_EDGES * 16 + 255) / 256, 256, 0, stream>>>(EoutP, Eg, scshE, M_EDGES * 16);
}

// Round 2
// 1173.626 us; speedup vs baseline: 1.9085x; 1.9085x over previous
//
#include <hip/hip_runtime.h>
#include <hip/hip_bf16.h>

#define N_NODES 50000
#define M_EDGES 800000
#define LEAKY_F 0.2f
#define BN_EPS 1e-5f

__device__ __forceinline__ float leaky(float x) { return x >= 0.f ? x : LEAKY_F * x; }

// ================= CSR build =================
__global__ __launch_bounds__(256) void hist_k(const int* __restrict__ dst,
                                              int* __restrict__ counts) {
  int e = blockIdx.x * 256 + threadIdx.x;
  if (e < M_EDGES) atomicAdd(&counts[dst[e]], 1);
}

// single block: exclusive scan of counts -> offs, copy to cursor, offs[N]=M
__global__ __launch_bounds__(256) void scan_k(const int* __restrict__ counts,
                                              int* __restrict__ offs,
                                              int* __restrict__ cursor) {
  __shared__ int chunk[256];
  const int CH = (N_NODES + 255) / 256;  // 196
  int tid = threadIdx.x;
  int beg = tid * CH, end = min(beg + CH, N_NODES);
  int s = 0;
  for (int i = beg; i < end; ++i) s += counts[i];
  chunk[tid] = s;
  __syncthreads();
  if (tid == 0) {
    int run = 0;
    for (int i = 0; i < 256; ++i) { int c = chunk[i]; chunk[i] = run; run += c; }
  }
  __syncthreads();
  int base = chunk[tid];
  for (int i = beg; i < end; ++i) {
    offs[i] = base;
    cursor[i] = base;
    base += counts[i];
  }
  if (tid == 0) offs[N_NODES] = M_EDGES;
}

__global__ __launch_bounds__(256) void fill_k(const int* __restrict__ src,
                                              const int* __restrict__ dst,
                                              int* __restrict__ cursor,
                                              int* __restrict__ ssrc) {
  int e = blockIdx.x * 256 + threadIdx.x;
  if (e >= M_EDGES) return;
  int p = atomicAdd(&cursor[dst[e]], 1);
  ssrc[p] = src[e];
}

// ---- segment gather-sum: O[n] = sum over CSR segment of X[ssrc[i]] (wave per node) ----
__global__ __launch_bounds__(256) void gather_seg_k(const float* __restrict__ X,
                                                    const int* __restrict__ offs,
                                                    const int* __restrict__ ssrc,
                                                    float* __restrict__ O) {
  int n = blockIdx.x * 4 + (threadIdx.x >> 6);
  int j = threadIdx.x & 63;
  int beg = offs[n], end = offs[n + 1];
  float acc = 0.f;
  int i = beg;
  for (; i + 1 < end; i += 2) {
    int s0 = ssrc[i], s1 = ssrc[i + 1];
    float a = X[(size_t)s0 * 64 + j];
    float b = X[(size_t)s1 * 64 + j];
    acc += a + b;
  }
  if (i < end) acc += X[(size_t)ssrc[i] * 64 + j];
  O[(size_t)n * 64 + j] = acc;
}

// ---- node1: s1 = A@W0+b0 ; s2 = A@W1 + s1@W2 + b1+b2   (row-local, 4 rows/block) ----
__global__ __launch_bounds__(256) void node1_k(
    const float* __restrict__ A, const float* __restrict__ W_ops,
    const float* __restrict__ b_ops, float* __restrict__ s1g, float* __restrict__ s2g) {
  __shared__ float W0[4096], W1[4096], W2[4096];
  __shared__ float rA[4][64], r1[4][64];
  int tid = threadIdx.x;
  for (int i = tid; i < 4096; i += 256) {
    W0[i] = W_ops[i];
    W1[i] = W_ops[4096 + i];
    W2[i] = W_ops[8192 + i];
  }
  int g = tid >> 6, j = tid & 63;
  size_t r = (size_t)blockIdx.x * 4 + g;
  rA[g][j] = A[r * 64 + j];
  __syncthreads();
  float acc = b_ops[j];
#pragma unroll
  for (int k = 0; k < 64; ++k) acc = fmaf(rA[g][k], W0[k * 64 + j], acc);
  r1[g][j] = acc;
  s1g[r * 64 + j] = acc;
  __syncthreads();
  float acc2 = b_ops[64 + j] + b_ops[128 + j];
#pragma unroll
  for (int k = 0; k < 64; ++k) {
    acc2 = fmaf(rA[g][k], W1[k * 64 + j], acc2);
    acc2 = fmaf(r1[g][k], W2[k * 64 + j], acc2);
  }
  s2g[r * 64 + j] = acc2;
}

// ---- node2: s3 = B@W3 + s2@W4 + b3+b4 ; Vnew = s1@Wc0+s2@Wc1+s3@Wc2+bcat ;
//             Ps = Vnew@Ws[0:64]+bS ; Pd = Vnew@Ws[128:192] ----
__global__ __launch_bounds__(256) void node2_k(
    const float* __restrict__ Bg, const float* __restrict__ s1g, const float* __restrict__ s2g,
    const float* __restrict__ W_ops, const float* __restrict__ b_ops,
    const float* __restrict__ W_cat, const float* __restrict__ b_cat,
    const float* __restrict__ W_S, const float* __restrict__ b_S,
    float* __restrict__ Vnew, float* __restrict__ Ps, float* __restrict__ Pd) {
  __shared__ float W3[4096], W4[4096], Wc0[4096], Wc1[4096], Wc2[4096], Ws0[4096], Ws2[4096];
  __shared__ float rB[4][64], r1[4][64], r2[4][64], r3[4][64], rV[4][64];
  int tid = threadIdx.x;
  for (int i = tid; i < 4096; i += 256) {
    W3[i] = W_ops[3 * 4096 + i];
    W4[i] = W_ops[4 * 4096 + i];
    Wc0[i] = W_cat[i];
    Wc1[i] = W_cat[4096 + i];
    Wc2[i] = W_cat[8192 + i];
    Ws0[i] = W_S[i];
    Ws2[i] = W_S[8192 + i];
  }
  int g = tid >> 6, j = tid & 63;
  size_t r = (size_t)blockIdx.x * 4 + g;
  rB[g][j] = Bg[r * 64 + j];
  r1[g][j] = s1g[r * 64 + j];
  r2[g][j] = s2g[r * 64 + j];
  __syncthreads();
  float a3 = b_ops[192 + j] + b_ops[256 + j];
#pragma unroll
  for (int k = 0; k < 64; ++k) {
    a3 = fmaf(rB[g][k], W3[k * 64 + j], a3);
    a3 = fmaf(r2[g][k], W4[k * 64 + j], a3);
  }
  r3[g][j] = a3;
  __syncthreads();
  float v = b_cat[j];
#pragma unroll
  for (int k = 0; k < 64; ++k) {
    v = fmaf(r1[g][k], Wc0[k * 64 + j], v);
    v = fmaf(r2[g][k], Wc1[k * 64 + j], v);
    v = fmaf(r3[g][k], Wc2[k * 64 + j], v);
  }
  rV[g][j] = v;
  Vnew[r * 64 + j] = v;
  __syncthreads();
  float ps = b_S[j], pd = 0.f;
#pragma unroll
  for (int k = 0; k < 64; ++k) {
    ps = fmaf(rV[g][k], Ws0[k * 64 + j], ps);
    pd = fmaf(rV[g][k], Ws2[k * 64 + j], pd);
  }
  Ps[r * 64 + j] = ps;
  Pd[r * 64 + j] = pd;
}

// ---- edge: Eout[e] = Ps[src[e]] + Pd[dst[e]] + leaky(E[e]) @ Wmid  (64 edges/block) ----
__global__ __launch_bounds__(256) void edge_k(
    const float* __restrict__ Eg, const int* __restrict__ src, const int* __restrict__ dst,
    const float* __restrict__ Ps, const float* __restrict__ Pd,
    const float* __restrict__ W_S, float* __restrict__ Eout) {
  __shared__ float Wm[4096];
  __shared__ float Ea[64][65];
  int tid = threadIdx.x;
  for (int i = tid; i < 4096; i += 256) Wm[i] = W_S[4096 + i];
  int e0 = blockIdx.x * 64;
  for (int q = tid; q < 1024; q += 256) {
    int e = q >> 4, kq = q & 15;
    float4 vv = reinterpret_cast<const float4*>(Eg)[(size_t)(e0 + e) * 16 + kq];
    Ea[e][kq * 4 + 0] = leaky(vv.x);
    Ea[e][kq * 4 + 1] = leaky(vv.y);
    Ea[e][kq * 4 + 2] = leaky(vv.z);
    Ea[e][kq * 4 + 3] = leaky(vv.w);
  }
  __syncthreads();
  int eq = tid & 15, cq = tid >> 4;
  int eb = eq * 4;
  float acc[4][4];
#pragma unroll
  for (int i = 0; i < 4; ++i) {
    int e = e0 + eb + i;
    int s = src[e], d = dst[e];
    float4 ps = reinterpret_cast<const float4*>(Ps)[(size_t)s * 16 + cq];
    float4 pd = reinterpret_cast<const float4*>(Pd)[(size_t)d * 16 + cq];
    acc[i][0] = ps.x + pd.x;
    acc[i][1] = ps.y + pd.y;
    acc[i][2] = ps.z + pd.z;
    acc[i][3] = ps.w + pd.w;
  }
#pragma unroll 8
  for (int k = 0; k < 64; ++k) {
    float4 w = *reinterpret_cast<const float4*>(&Wm[k * 64 + cq * 4]);
#pragma unroll
    for (int i = 0; i < 4; ++i) {
      float ea = Ea[eb + i][k];
      acc[i][0] = fmaf(ea, w.x, acc[i][0]);
      acc[i][1] = fmaf(ea, w.y, acc[i][1]);
      acc[i][2] = fmaf(ea, w.z, acc[i][2]);
      acc[i][3] = fmaf(ea, w.w, acc[i][3]);
    }
  }
#pragma unroll
  for (int i = 0; i < 4; ++i) {
    float4 st = make_float4(acc[i][0], acc[i][1], acc[i][2], acc[i][3]);
    reinterpret_cast<float4*>(Eout)[(size_t)(e0 + eb + i) * 16 + cq] = st;
  }
}

// ---- per-column sum / sumsq over rows (col = index % 64) ----
__global__ __launch_bounds__(256) void col_stats_k(
    const float* __restrict__ X, size_t nelem, float* __restrict__ sums) {
  __shared__ float ls[128];
  int tid = threadIdx.x;
  if (tid < 128) ls[tid] = 0.f;
  __syncthreads();
  int j = tid & 63;
  float s = 0.f, ss = 0.f;
  size_t stride = (size_t)gridDim.x * blockDim.x;
  for (size_t i = (size_t)blockIdx.x * blockDim.x + tid; i < nelem; i += stride) {
    float x = X[i];
    s += x;
    ss = fmaf(x, x, ss);
  }
  atomicAdd(&ls[j], s);
  atomicAdd(&ls[64 + j], ss);
  __syncthreads();
  if (tid < 128) atomicAdd(&sums[tid], ls[tid]);
}

__global__ void finalize_k(const float* __restrict__ sums, float inv_n,
                           const float* __restrict__ gamma, const float* __restrict__ beta,
                           float* __restrict__ sc_shift) {
  int j = threadIdx.x;
  float mu = sums[j] * inv_n;
  float var = sums[64 + j] * inv_n - mu * mu;
  float sc = gamma[j] * rsqrtf(var + BN_EPS);
  sc_shift[j] = sc;
  sc_shift[64 + j] = beta[j] - mu * sc;
}

// ---- in-place: X = leaky(X*sc + shift) + resid ----
__global__ __launch_bounds__(256) void bn_apply_k(
    float* __restrict__ X, const float* __restrict__ resid,
    const float* __restrict__ sc_shift, int n4) {
  int i = blockIdx.x * blockDim.x + threadIdx.x;
  if (i >= n4) return;
  int jq = i & 15;
  float4 x = reinterpret_cast<float4*>(X)[i];
  float4 r = reinterpret_cast<const float4*>(resid)[i];
  float4 sc = reinterpret_cast<const float4*>(sc_shift)[jq];
  float4 sh = reinterpret_cast<const float4*>(sc_shift + 64)[jq];
  float4 y;
  y.x = leaky(fmaf(x.x, sc.x, sh.x)) + r.x;
  y.y = leaky(fmaf(x.y, sc.y, sh.y)) + r.y;
  y.z = leaky(fmaf(x.z, sc.z, sh.z)) + r.z;
  y.w = leaky(fmaf(x.w, sc.w, sh.w)) + r.w;
  reinterpret_cast<float4*>(X)[i] = y;
}

extern "C" void kernel_launch(void* const* d_in, const int* in_sizes, int n_in,
                              void* d_out, int out_size, void* d_ws, size_t ws_size,
                              hipStream_t stream) {
  const float* V      = (const float*)d_in[0];
  const float* Eg     = (const float*)d_in[1];
  const int*   src    = (const int*)d_in[2];
  const int*   dst    = (const int*)d_in[3];
  const float* W_ops  = (const float*)d_in[4];
  const float* b_ops  = (const float*)d_in[5];
  const float* W_cat  = (const float*)d_in[6];
  const float* b_cat  = (const float*)d_in[7];
  const float* W_S    = (const float*)d_in[8];
  const float* b_S    = (const float*)d_in[9];
  const float* gammaV = (const float*)d_in[10];
  const float* betaV  = (const float*)d_in[11];
  const float* gammaE = (const float*)d_in[12];
  const float* betaE  = (const float*)d_in[13];

  float* ws = (float*)d_ws;
  const size_t ND = (size_t)N_NODES * 64;
  float* A      = ws;
  float* s1     = ws + ND;
  float* s2     = ws + 2 * ND;
  float* Bg     = ws + 3 * ND;
  float* Ps     = ws + 4 * ND;
  float* Pd     = ws + 5 * ND;
  float* statsV = ws + 6 * ND;    // 128 | 128 | 128 | 128
  float* statsE = statsV + 128;
  float* scshV  = statsV + 256;
  float* scshE  = statsV + 384;
  int* counts = (int*)(statsV + 512);
  int* offs   = counts + N_NODES;          // N+1
  int* cursor = offs + N_NODES + 1;
  int* ssrc   = cursor + N_NODES;          // M

  float* Vout = (float*)d_out;
  float* EoutP = Vout + ND;

  hipMemsetAsync(counts, 0, N_NODES * sizeof(int), stream);
  hipMemsetAsync(statsV, 0, 256 * sizeof(float), stream);

  const int eb = (M_EDGES + 255) / 256;
  hist_k<<<eb, 256, 0, stream>>>(dst, counts);
  scan_k<<<1, 256, 0, stream>>>(counts, offs, cursor);
  fill_k<<<eb, 256, 0, stream>>>(src, dst, cursor, ssrc);

  gather_seg_k<<<N_NODES / 4, 256, 0, stream>>>(V, offs, ssrc, A);
  node1_k<<<N_NODES / 4, 256, 0, stream>>>(A, W_ops, b_ops, s1, s2);
  gather_seg_k<<<N_NODES / 4, 256, 0, stream>>>(s1, offs, ssrc, Bg);
  node2_k<<<N_NODES / 4, 256, 0, stream>>>(Bg, s1, s2, W_ops, b_ops, W_cat, b_cat,
                                           W_S, b_S, Vout, Ps, Pd);
  edge_k<<<M_EDGES / 64, 256, 0, stream>>>(Eg, src, dst, Ps, Pd, W_S, EoutP);
  col_stats_k<<<1024, 256, 0, stream>>>(Vout, ND, statsV);
  col_stats_k<<<2048, 256, 0, stream>>>(EoutP, (size_t)M_EDGES * 64, statsE);
  finalize_k<<<1, 64, 0, stream>>>(statsV, 1.f / N_NODES, gammaV, betaV, scshV);
  finalize_k<<<1, 64, 0, stream>>>(statsE, 1.f / M_EDGES, gammaE, betaE, scshE);
  bn_apply_k<<<(int)((ND / 4 + 255) / 256), 256, 0, stream>>>(Vout, V, scshV, (int)(ND / 4));
  bn_apply_k<<<(M_EDGES * 16 + 255) / 256, 256, 0, stream>>>(EoutP, Eg, scshE, M_EDGES * 16);
}

// Round 3
// 913.042 us; speedup vs baseline: 2.4532x; 1.2854x over previous
//
#include <hip/hip_runtime.h>
#include <hip/hip_bf16.h>

#define N_NODES 50000
#define M_EDGES 800000
#define LEAKY_F 0.2f
#define BN_EPS 1e-5f

__device__ __forceinline__ float leaky(float x) { return x >= 0.f ? x : LEAKY_F * x; }

// ================= CSR build =================
__global__ __launch_bounds__(256) void hist_k(const int* __restrict__ dst,
                                              int* __restrict__ counts) {
  int e = blockIdx.x * 256 + threadIdx.x;
  if (e < M_EDGES) atomicAdd(&counts[dst[e]], 1);
}

__global__ __launch_bounds__(256) void scan_k(const int* __restrict__ counts,
                                              int* __restrict__ offs,
                                              int* __restrict__ cursor) {
  __shared__ int chunk[256];
  const int CH = (N_NODES + 255) / 256;
  int tid = threadIdx.x;
  int beg = tid * CH, end = min(beg + CH, N_NODES);
  int s = 0;
  for (int i = beg; i < end; ++i) s += counts[i];
  chunk[tid] = s;
  __syncthreads();
  if (tid == 0) {
    int run = 0;
    for (int i = 0; i < 256; ++i) { int c = chunk[i]; chunk[i] = run; run += c; }
  }
  __syncthreads();
  int base = chunk[tid];
  for (int i = beg; i < end; ++i) {
    offs[i] = base;
    cursor[i] = base;
    base += counts[i];
  }
  if (tid == 0) offs[N_NODES] = M_EDGES;
}

__global__ __launch_bounds__(256) void fill_k(const int* __restrict__ src,
                                              const int* __restrict__ dst,
                                              int* __restrict__ cursor,
                                              int* __restrict__ ssrc) {
  int e = blockIdx.x * 256 + threadIdx.x;
  if (e >= M_EDGES) return;
  int p = atomicAdd(&cursor[dst[e]], 1);
  ssrc[p] = src[e];
}

// ---- segment gather-sum, wave per node, 4x unrolled ----
__global__ __launch_bounds__(256) void gather_seg_k(const float* __restrict__ X,
                                                    const int* __restrict__ offs,
                                                    const int* __restrict__ ssrc,
                                                    float* __restrict__ O) {
  int n = blockIdx.x * 4 + (threadIdx.x >> 6);
  int j = threadIdx.x & 63;
  int beg = offs[n], end = offs[n + 1];
  float acc = 0.f;
  int i = beg;
  for (; i + 3 < end; i += 4) {
    int s0 = ssrc[i], s1 = ssrc[i + 1], s2 = ssrc[i + 2], s3 = ssrc[i + 3];
    float a = X[(size_t)s0 * 64 + j];
    float b = X[(size_t)s1 * 64 + j];
    float c = X[(size_t)s2 * 64 + j];
    float d = X[(size_t)s3 * 64 + j];
    acc += (a + b) + (c + d);
  }
  for (; i < end; ++i) acc += X[(size_t)ssrc[i] * 64 + j];
  O[(size_t)n * 64 + j] = acc;
}

// ================= weight-prep (algebraic collapse) =================
// prep1: block0: W12 = W1 + W0@W2 ; block1: Wc12 = Wc1 + W4@Wc2
__global__ __launch_bounds__(256) void prep1_k(const float* __restrict__ W_ops,
                                               const float* __restrict__ W_cat,
                                               float* __restrict__ W12g,
                                               float* __restrict__ Wc12g) {
  __shared__ float Wa[4096], Wb[4096];
  int tid = threadIdx.x;
  const float *Am, *Bm, *Add;
  float* Out;
  if (blockIdx.x == 0) { Am = W_ops; Bm = W_ops + 8192; Add = W_ops + 4096; Out = W12g; }
  else { Am = W_ops + 16384; Bm = W_cat + 8192; Add = W_cat + 4096; Out = Wc12g; }
  for (int i = tid; i < 4096; i += 256) { Wa[i] = Am[i]; Wb[i] = Bm[i]; }
  __syncthreads();
  for (int t = 0; t < 16; ++t) {
    int o = tid + t * 256;
    int r = o >> 6, j = o & 63;
    float acc = Add[o];
#pragma unroll
    for (int k = 0; k < 64; ++k) acc = fmaf(Wa[r * 64 + k], Wb[k * 64 + j], acc);
    Out[o] = acc;
  }
}

// prep2: block0: WA = W0@Wc0 + W12@Wc12 ; block1: WB = W3@Wc2 and bias c
__global__ __launch_bounds__(256) void prep2_k(const float* __restrict__ W_ops,
                                               const float* __restrict__ b_ops,
                                               const float* __restrict__ W_cat,
                                               const float* __restrict__ b_cat,
                                               const float* __restrict__ W12g,
                                               const float* __restrict__ Wc12g,
                                               float* __restrict__ WAg,
                                               float* __restrict__ WBg,
                                               float* __restrict__ cg) {
  __shared__ float M0[4096], M1[4096], M2[4096], M3[4096], M4[4096];
  __shared__ float bb[64];
  int tid = threadIdx.x;
  if (blockIdx.x == 0) {
    for (int i = tid; i < 4096; i += 256) {
      M0[i] = W_ops[i];        // W0
      M1[i] = W_cat[i];        // Wc0
      M2[i] = W12g[i];
      M3[i] = Wc12g[i];
    }
    __syncthreads();
    for (int t = 0; t < 16; ++t) {
      int o = tid + t * 256;
      int r = o >> 6, j = o & 63;
      float acc = 0.f;
#pragma unroll
      for (int k = 0; k < 64; ++k) {
        acc = fmaf(M0[r * 64 + k], M1[k * 64 + j], acc);
        acc = fmaf(M2[r * 64 + k], M3[k * 64 + j], acc);
      }
      WAg[o] = acc;
    }
  } else {
    for (int i = tid; i < 4096; i += 256) {
      M0[i] = W_ops[3 * 4096 + i];  // W3
      M1[i] = W_cat[8192 + i];      // Wc2
      M2[i] = W_ops[2 * 4096 + i];  // W2
      M3[i] = W_cat[i];             // Wc0
      M4[i] = Wc12g[i];
    }
    __syncthreads();
    for (int t = 0; t < 16; ++t) {
      int o = tid + t * 256;
      int r = o >> 6, j = o & 63;
      float acc = 0.f;
#pragma unroll
      for (int k = 0; k < 64; ++k) acc = fmaf(M0[r * 64 + k], M1[k * 64 + j], acc);
      WBg[o] = acc;
    }
    if (tid < 64) {   // bb = b12 = b0@W2 + b1 + b2
      int j = tid;
      float acc = b_ops[64 + j] + b_ops[128 + j];
#pragma unroll
      for (int k = 0; k < 64; ++k) acc = fmaf(b_ops[k], M2[k * 64 + j], acc);
      bb[j] = acc;
    }
    __syncthreads();
    if (tid < 64) {   // c = b0@Wc0 + b12@Wc12 + (b3+b4)@Wc2 + bcat
      int j = tid;
      float acc = b_cat[j];
#pragma unroll
      for (int k = 0; k < 64; ++k) {
        acc = fmaf(b_ops[k], M3[k * 64 + j], acc);
        acc = fmaf(bb[k], M4[k * 64 + j], acc);
        acc = fmaf(b_ops[192 + k] + b_ops[256 + k], M1[k * 64 + j], acc);
      }
      cg[j] = acc;
    }
  }
}

// ================= row-register matmul kernels =================
// s1 = A@W0 + b0
__global__ __launch_bounds__(256) void rowmm1_k(const float* __restrict__ A,
                                                const float* __restrict__ W_ops,
                                                const float* __restrict__ b_ops,
                                                float* __restrict__ s1) {
  __shared__ float W[4096];
  __shared__ float bias[64];
  int tid = threadIdx.x;
  for (int i = tid; i < 4096; i += 256) W[i] = W_ops[i];
  if (tid < 64) bias[tid] = b_ops[tid];
  __syncthreads();
  int r = blockIdx.x * 256 + tid;
  if (r >= N_NODES) return;
  float x[64];
  const float4* Xr = reinterpret_cast<const float4*>(A + (size_t)r * 64);
#pragma unroll
  for (int q = 0; q < 16; ++q) {
    float4 v = Xr[q];
    x[q * 4] = v.x; x[q * 4 + 1] = v.y; x[q * 4 + 2] = v.z; x[q * 4 + 3] = v.w;
  }
  float4* Or = reinterpret_cast<float4*>(s1 + (size_t)r * 64);
  for (int j0 = 0; j0 < 64; j0 += 4) {
    float a0 = bias[j0], a1 = bias[j0 + 1], a2 = bias[j0 + 2], a3 = bias[j0 + 3];
#pragma unroll
    for (int k = 0; k < 64; ++k) {
      float4 w = *reinterpret_cast<const float4*>(&W[k * 64 + j0]);
      a0 = fmaf(x[k], w.x, a0);
      a1 = fmaf(x[k], w.y, a1);
      a2 = fmaf(x[k], w.z, a2);
      a3 = fmaf(x[k], w.w, a3);
    }
    Or[j0 >> 2] = make_float4(a0, a1, a2, a3);
  }
}

// Vnew = A@WA + B@WB + c
__global__ __launch_bounds__(256) void vnew_k(const float* __restrict__ A,
                                              const float* __restrict__ B,
                                              const float* __restrict__ WAg,
                                              const float* __restrict__ WBg,
                                              const float* __restrict__ cg,
                                              float* __restrict__ Vnew) {
  __shared__ float WA[4096], WB[4096];
  __shared__ float cb[64];
  int tid = threadIdx.x;
  for (int i = tid; i < 4096; i += 256) { WA[i] = WAg[i]; WB[i] = WBg[i]; }
  if (tid < 64) cb[tid] = cg[tid];
  __syncthreads();
  int r = blockIdx.x * 256 + tid;
  if (r >= N_NODES) return;
  float xa[64], xb[64];
  const float4* Ar = reinterpret_cast<const float4*>(A + (size_t)r * 64);
  const float4* Br = reinterpret_cast<const float4*>(B + (size_t)r * 64);
#pragma unroll
  for (int q = 0; q < 16; ++q) {
    float4 va = Ar[q];
    xa[q * 4] = va.x; xa[q * 4 + 1] = va.y; xa[q * 4 + 2] = va.z; xa[q * 4 + 3] = va.w;
    float4 vb = Br[q];
    xb[q * 4] = vb.x; xb[q * 4 + 1] = vb.y; xb[q * 4 + 2] = vb.z; xb[q * 4 + 3] = vb.w;
  }
  float4* Or = reinterpret_cast<float4*>(Vnew + (size_t)r * 64);
  for (int j0 = 0; j0 < 64; j0 += 4) {
    float a0 = cb[j0], a1 = cb[j0 + 1], a2 = cb[j0 + 2], a3 = cb[j0 + 3];
#pragma unroll
    for (int k = 0; k < 64; ++k) {
      float4 wa = *reinterpret_cast<const float4*>(&WA[k * 64 + j0]);
      a0 = fmaf(xa[k], wa.x, a0);
      a1 = fmaf(xa[k], wa.y, a1);
      a2 = fmaf(xa[k], wa.z, a2);
      a3 = fmaf(xa[k], wa.w, a3);
      float4 wb = *reinterpret_cast<const float4*>(&WB[k * 64 + j0]);
      a0 = fmaf(xb[k], wb.x, a0);
      a1 = fmaf(xb[k], wb.y, a1);
      a2 = fmaf(xb[k], wb.z, a2);
      a3 = fmaf(xb[k], wb.w, a3);
    }
    Or[j0 >> 2] = make_float4(a0, a1, a2, a3);
  }
}

// Ps = Vnew@Ws0 + bS ; Pd = Vnew@Ws2
__global__ __launch_bounds__(256) void proj_k(const float* __restrict__ Vnew,
                                              const float* __restrict__ W_S,
                                              const float* __restrict__ b_S,
                                              float* __restrict__ Ps,
                                              float* __restrict__ Pd) {
  __shared__ float W0s[4096], W2s[4096];
  __shared__ float bias[64];
  int tid = threadIdx.x;
  for (int i = tid; i < 4096; i += 256) { W0s[i] = W_S[i]; W2s[i] = W_S[8192 + i]; }
  if (tid < 64) bias[tid] = b_S[tid];
  __syncthreads();
  int r = blockIdx.x * 256 + tid;
  if (r >= N_NODES) return;
  float x[64];
  const float4* Xr = reinterpret_cast<const float4*>(Vnew + (size_t)r * 64);
#pragma unroll
  for (int q = 0; q < 16; ++q) {
    float4 v = Xr[q];
    x[q * 4] = v.x; x[q * 4 + 1] = v.y; x[q * 4 + 2] = v.z; x[q * 4 + 3] = v.w;
  }
  float4* Osr = reinterpret_cast<float4*>(Ps + (size_t)r * 64);
  float4* Odr = reinterpret_cast<float4*>(Pd + (size_t)r * 64);
  for (int j0 = 0; j0 < 64; j0 += 4) {
    float a0 = bias[j0], a1 = bias[j0 + 1], a2 = bias[j0 + 2], a3 = bias[j0 + 3];
    float d0 = 0.f, d1 = 0.f, d2 = 0.f, d3 = 0.f;
#pragma unroll
    for (int k = 0; k < 64; ++k) {
      float xk = x[k];
      float4 w = *reinterpret_cast<const float4*>(&W0s[k * 64 + j0]);
      a0 = fmaf(xk, w.x, a0);
      a1 = fmaf(xk, w.y, a1);
      a2 = fmaf(xk, w.z, a2);
      a3 = fmaf(xk, w.w, a3);
      float4 u = *reinterpret_cast<const float4*>(&W2s[k * 64 + j0]);
      d0 = fmaf(xk, u.x, d0);
      d1 = fmaf(xk, u.y, d1);
      d2 = fmaf(xk, u.z, d2);
      d3 = fmaf(xk, u.w, d3);
    }
    Osr[j0 >> 2] = make_float4(a0, a1, a2, a3);
    Odr[j0 >> 2] = make_float4(d0, d1, d2, d3);
  }
}

// ---- edge: Eout[e] = Ps[src[e]] + Pd[dst[e]] + leaky(E[e]) @ Wmid ; fused col-stats ----
__global__ __launch_bounds__(256) void edge_k(
    const float* __restrict__ Eg, const int* __restrict__ src, const int* __restrict__ dst,
    const float* __restrict__ Ps, const float* __restrict__ Pd,
    const float* __restrict__ W_S, float* __restrict__ Eout, float* __restrict__ stats) {
  __shared__ float Wm[4096];
  __shared__ float Ea[64][65];
  __shared__ float ls[128];
  int tid = threadIdx.x;
  for (int i = tid; i < 4096; i += 256) Wm[i] = W_S[4096 + i];
  if (tid < 128) ls[tid] = 0.f;
  int e0 = blockIdx.x * 64;
  for (int q = tid; q < 1024; q += 256) {
    int e = q >> 4, kq = q & 15;
    float4 vv = reinterpret_cast<const float4*>(Eg)[(size_t)(e0 + e) * 16 + kq];
    Ea[e][kq * 4 + 0] = leaky(vv.x);
    Ea[e][kq * 4 + 1] = leaky(vv.y);
    Ea[e][kq * 4 + 2] = leaky(vv.z);
    Ea[e][kq * 4 + 3] = leaky(vv.w);
  }
  __syncthreads();
  int eq = tid & 15, cq = tid >> 4;
  int eb = eq * 4;
  float acc[4][4];
#pragma unroll
  for (int i = 0; i < 4; ++i) {
    int e = e0 + eb + i;
    int s = src[e], d = dst[e];
    float4 ps = reinterpret_cast<const float4*>(Ps)[(size_t)s * 16 + cq];
    float4 pd = reinterpret_cast<const float4*>(Pd)[(size_t)d * 16 + cq];
    acc[i][0] = ps.x + pd.x;
    acc[i][1] = ps.y + pd.y;
    acc[i][2] = ps.z + pd.z;
    acc[i][3] = ps.w + pd.w;
  }
#pragma unroll 8
  for (int k = 0; k < 64; ++k) {
    float4 w = *reinterpret_cast<const float4*>(&Wm[k * 64 + cq * 4]);
#pragma unroll
    for (int i = 0; i < 4; ++i) {
      float ea = Ea[eb + i][k];
      acc[i][0] = fmaf(ea, w.x, acc[i][0]);
      acc[i][1] = fmaf(ea, w.y, acc[i][1]);
      acc[i][2] = fmaf(ea, w.z, acc[i][2]);
      acc[i][3] = fmaf(ea, w.w, acc[i][3]);
    }
  }
  float s4[4], q4[4];
#pragma unroll
  for (int c = 0; c < 4; ++c) { s4[c] = 0.f; q4[c] = 0.f; }
#pragma unroll
  for (int i = 0; i < 4; ++i) {
    float4 st = make_float4(acc[i][0], acc[i][1], acc[i][2], acc[i][3]);
    reinterpret_cast<float4*>(Eout)[(size_t)(e0 + eb + i) * 16 + cq] = st;
#pragma unroll
    for (int c = 0; c < 4; ++c) {
      s4[c] += acc[i][c];
      q4[c] = fmaf(acc[i][c], acc[i][c], q4[c]);
    }
  }
#pragma unroll
  for (int c = 0; c < 4; ++c) {
    atomicAdd(&ls[cq * 4 + c], s4[c]);
    atomicAdd(&ls[64 + cq * 4 + c], q4[c]);
  }
  __syncthreads();
  if (tid < 128) atomicAdd(&stats[tid], ls[tid]);
}

// ---- per-column sum / sumsq (for V side) ----
__global__ __launch_bounds__(256) void col_stats_k(
    const float* __restrict__ X, size_t nelem, float* __restrict__ sums) {
  __shared__ float ls[128];
  int tid = threadIdx.x;
  if (tid < 128) ls[tid] = 0.f;
  __syncthreads();
  int j = tid & 63;
  float s = 0.f, ss = 0.f;
  size_t stride = (size_t)gridDim.x * blockDim.x;
  for (size_t i = (size_t)blockIdx.x * blockDim.x + tid; i < nelem; i += stride) {
    float x = X[i];
    s += x;
    ss = fmaf(x, x, ss);
  }
  atomicAdd(&ls[j], s);
  atomicAdd(&ls[64 + j], ss);
  __syncthreads();
  if (tid < 128) atomicAdd(&sums[tid], ls[tid]);
}

__global__ void finalize_k(const float* __restrict__ sums, float inv_n,
                           const float* __restrict__ gamma, const float* __restrict__ beta,
                           float* __restrict__ sc_shift) {
  int j = threadIdx.x;
  float mu = sums[j] * inv_n;
  float var = sums[64 + j] * inv_n - mu * mu;
  float sc = gamma[j] * rsqrtf(var + BN_EPS);
  sc_shift[j] = sc;
  sc_shift[64 + j] = beta[j] - mu * sc;
}

__global__ __launch_bounds__(256) void bn_apply_k(
    float* __restrict__ X, const float* __restrict__ resid,
    const float* __restrict__ sc_shift, int n4) {
  int i = blockIdx.x * blockDim.x + threadIdx.x;
  if (i >= n4) return;
  int jq = i & 15;
  float4 x = reinterpret_cast<float4*>(X)[i];
  float4 r = reinterpret_cast<const float4*>(resid)[i];
  float4 sc = reinterpret_cast<const float4*>(sc_shift)[jq];
  float4 sh = reinterpret_cast<const float4*>(sc_shift + 64)[jq];
  float4 y;
  y.x = leaky(fmaf(x.x, sc.x, sh.x)) + r.x;
  y.y = leaky(fmaf(x.y, sc.y, sh.y)) + r.y;
  y.z = leaky(fmaf(x.z, sc.z, sh.z)) + r.z;
  y.w = leaky(fmaf(x.w, sc.w, sh.w)) + r.w;
  reinterpret_cast<float4*>(X)[i] = y;
}

extern "C" void kernel_launch(void* const* d_in, const int* in_sizes, int n_in,
                              void* d_out, int out_size, void* d_ws, size_t ws_size,
                              hipStream_t stream) {
  const float* V      = (const float*)d_in[0];
  const float* Eg     = (const float*)d_in[1];
  const int*   src    = (const int*)d_in[2];
  const int*   dst    = (const int*)d_in[3];
  const float* W_ops  = (const float*)d_in[4];
  const float* b_ops  = (const float*)d_in[5];
  const float* W_cat  = (const float*)d_in[6];
  const float* b_cat  = (const float*)d_in[7];
  const float* W_S    = (const float*)d_in[8];
  const float* b_S    = (const float*)d_in[9];
  const float* gammaV = (const float*)d_in[10];
  const float* betaV  = (const float*)d_in[11];
  const float* gammaE = (const float*)d_in[12];
  const float* betaE  = (const float*)d_in[13];

  float* ws = (float*)d_ws;
  const size_t ND = (size_t)N_NODES * 64;
  float* A    = ws;
  float* s1   = ws + ND;
  float* Bg   = ws + 2 * ND;
  float* Ps   = ws + 3 * ND;
  float* Pd   = ws + 4 * ND;
  float* xb   = ws + 5 * ND;
  float* W12g  = xb;
  float* Wc12g = xb + 4096;
  float* WAg   = xb + 8192;
  float* WBg   = xb + 12288;
  float* cg    = xb + 16384;
  float* statsV = xb + 16448;
  float* statsE = statsV + 128;
  float* scshV  = statsV + 256;
  float* scshE  = statsV + 384;
  int* counts = (int*)(statsV + 512);
  int* offs   = counts + N_NODES;
  int* cursor = offs + N_NODES + 1;
  int* ssrc   = cursor + N_NODES;

  float* Vout  = (float*)d_out;
  float* EoutP = Vout + ND;

  hipMemsetAsync(counts, 0, N_NODES * sizeof(int), stream);
  hipMemsetAsync(statsV, 0, 256 * sizeof(float), stream);

  const int eb = (M_EDGES + 255) / 256;
  const int rb = (N_NODES + 255) / 256;
  prep1_k<<<2, 256, 0, stream>>>(W_ops, W_cat, W12g, Wc12g);
  prep2_k<<<2, 256, 0, stream>>>(W_ops, b_ops, W_cat, b_cat, W12g, Wc12g, WAg, WBg, cg);
  hist_k<<<eb, 256, 0, stream>>>(dst, counts);
  scan_k<<<1, 256, 0, stream>>>(counts, offs, cursor);
  fill_k<<<eb, 256, 0, stream>>>(src, dst, cursor, ssrc);

  gather_seg_k<<<N_NODES / 4, 256, 0, stream>>>(V, offs, ssrc, A);
  rowmm1_k<<<rb, 256, 0, stream>>>(A, W_ops, b_ops, s1);
  gather_seg_k<<<N_NODES / 4, 256, 0, stream>>>(s1, offs, ssrc, Bg);
  vnew_k<<<rb, 256, 0, stream>>>(A, Bg, WAg, WBg, cg, Vout);
  proj_k<<<rb, 256, 0, stream>>>(Vout, W_S, b_S, Ps, Pd);
  edge_k<<<M_EDGES / 64, 256, 0, stream>>>(Eg, src, dst, Ps, Pd, W_S, EoutP, statsE);
  col_stats_k<<<512, 256, 0, stream>>>(Vout, ND, statsV);
  finalize_k<<<1, 64, 0, stream>>>(statsV, 1.f / N_NODES, gammaV, betaV, scshV);
  finalize_k<<<1, 64, 0, stream>>>(statsE, 1.f / M_EDGES, gammaE, betaE, scshE);
  bn_apply_k<<<(int)((ND / 4 + 255) / 256), 256, 0, stream>>>(Vout, V, scshV, (int)(ND / 4));
  bn_apply_k<<<(M_EDGES * 16 + 255) / 256, 256, 0, stream>>>(EoutP, Eg, scshE, M_EDGES * 16);
}